// Round 7
// baseline (161.929 us; speedup 1.0000x reference)
//
#include <hip/hip_runtime.h>

#define D      256
#define NROWS  8192
#define BHALF  4096
#define AT     64                       // A-tile rows (LDS panel)
#define BT     128                      // B-tile rows per block
#define NA     (NROWS / AT)             // 128
#define NC     (NROWS / BT)             // 64
#define NPAIR  4160                     // sum_a (64 - (a>>1))
#define NGRID  1024                     // 4 blocks/CU target
#define NBINS  64

typedef __attribute__((ext_vector_type(8))) short  short8;
typedef __attribute__((ext_vector_type(4))) float  f32x4;

#if __has_builtin(__builtin_amdgcn_exp2f)
#define EXP2F(x) __builtin_amdgcn_exp2f(x)
#else
#define EXP2F(x) exp2f(x)
#endif

// ws layout (memset zeroes [0..2048)):
//   0     double sumsq
//   8     unsigned counter
//   16    double bins[64]          -> ends 528
//   1024  float colsum[256]        -> ends 2048
//   4096  float sq[8192]           -> ends 36864
//   36864 bf16 Tb[8192][256] (4 MB) -> ends 4231168 (proven < ws_size)

__device__ __forceinline__ unsigned short f2bf(float f) {
    unsigned u = __builtin_bit_cast(unsigned, f);
    unsigned r = (u + 0x7fffu + ((u >> 16) & 1u)) >> 16;   // RNE (no NaN in data)
    return (unsigned short)r;
}

__device__ __forceinline__ void gload_lds16(const unsigned short* g, unsigned short* l) {
    __builtin_amdgcn_global_load_lds(
        (const __attribute__((address_space(1))) unsigned int*)g,
        (__attribute__((address_space(3))) unsigned int*)l,
        16, 0, 0);
}

// ---------------------------------------------------------------- pass 1
__global__ __launch_bounds__(256)
void pre_kernel(const float* __restrict__ src, const float* __restrict__ tar,
                float* __restrict__ sq, float* __restrict__ colsum,
                double* __restrict__ sumsq, unsigned short* __restrict__ Tb) {
    __shared__ float cs[D];
    int t = threadIdx.x;
    cs[t] = 0.f;
    __syncthreads();

    int lane = t & 63, w = t >> 6;
    int rowBase = blockIdx.x * 32 + w * 8;

    float4 v[8];
    #pragma unroll
    for (int it = 0; it < 8; ++it) {
        int r = rowBase + it;
        const float* rowp = (r < BHALF) ? (src + (size_t)r * D)
                                        : (tar + (size_t)(r - BHALF) * D);
        v[it] = *(const float4*)(rowp + lane * 4);
    }

    float4 csum = make_float4(0.f, 0.f, 0.f, 0.f);
    float sqacc = 0.f;
    #pragma unroll
    for (int it = 0; it < 8; ++it) {
        int r = rowBase + it;
        ushort4 h;
        h.x = f2bf(v[it].x); h.y = f2bf(v[it].y);
        h.z = f2bf(v[it].z); h.w = f2bf(v[it].w);
        *(ushort4*)(Tb + (size_t)r * D + lane * 4) = h;
        csum.x += v[it].x; csum.y += v[it].y; csum.z += v[it].z; csum.w += v[it].w;
        float s = v[it].x * v[it].x + v[it].y * v[it].y +
                  v[it].z * v[it].z + v[it].w * v[it].w;
        #pragma unroll
        for (int off = 32; off; off >>= 1) s += __shfl_xor(s, off, 64);
        if (lane == 0) { sq[r] = s; sqacc += s; }
    }
    atomicAdd(&cs[lane * 4 + 0], csum.x);
    atomicAdd(&cs[lane * 4 + 1], csum.y);
    atomicAdd(&cs[lane * 4 + 2], csum.z);
    atomicAdd(&cs[lane * 4 + 3], csum.w);
    if (lane == 0) atomicAdd(sumsq, (double)sqacc);
    __syncthreads();
    atomicAdd(&colsum[t], cs[t]);
}

// ---------------------------------------------------------------- main (persistent)
__global__ __launch_bounds__(256, 4)
void mmd_main(const unsigned short* __restrict__ Tb,
              const float* __restrict__ sq, const float* __restrict__ colsum,
              const double* __restrict__ sumsq,
              double* __restrict__ bins, unsigned* __restrict__ counter,
              float* __restrict__ out)
{
    __shared__ unsigned short As[AT * D];     // 32 KB: 64-row full-K A panel

    int t = threadIdx.x, lane = t & 63, wid = t >> 6;   // wid = B sub-band
    int lr = lane & 15, lk = lane >> 4;

    // XCD-contiguous pair runs (1024 % 8 == 0, bijective)
    int bid = blockIdx.x;
    int sw = (bid & 7) * (NGRID / 8) + (bid >> 3);
    int pstart = (int)(((long)sw * NPAIR) / NGRID);
    int pend   = (int)(((long)(sw + 1) * NPAIR) / NGRID);

    // pair p -> (a, c): a in 0..127, c in a>>1 .. 63
    int a, c;
    {
        int rem = pstart; a = 0;
        while (rem >= NC - (a >> 1)) { rem -= NC - (a >> 1); ++a; }
        c = (a >> 1) + rem;
    }

    // A staging: LDS linear [row][slot], slot holds global chunk slot^(row&7)
    auto stageA = [&](int aa) {
        const unsigned short* g = Tb + (size_t)aa * AT * D;
        #pragma unroll
        for (int p = 0; p < 8; ++p) {
            int q = p * 256 + t;            // 16B-chunk id, 0..2047
            int row = q >> 5, cc = q & 31;
            gload_lds16(g + row * D + ((cc ^ (row & 7)) << 3), &As[q << 3]);
        }
    };

    stageA(a);
    int staged_a = a;

    // bandwidth -> g2, per block (overlaps first A stage)
    float4 c4 = *(const float4*)(colsum + lane * 4);
    float s = c4.x * c4.x + c4.y * c4.y + c4.z * c4.z + c4.w * c4.w;
    #pragma unroll
    for (int off = 32; off; off >>= 1) s += __shfl_xor(s, off, 64);
    double sumL2 = 2.0 * (double)NROWS * (*sumsq) - 2.0 * (double)s;
    double bwd = sumL2 / ((double)NROWS * (double)NROWS - (double)NROWS) / 4.0;
    float g2  = (float)(1.4426950408889634 / (16.0 * bwd));
    float g22 = 2.f * g2;

    asm volatile("s_waitcnt vmcnt(0)" ::: "memory");
    __syncthreads();                            // first A panel ready

    for (int p = pstart; p < pend; ++p) {
        if (a != staged_a) {                    // block-uniform condition
            __syncthreads();                    // everyone done with old panel
            stageA(a);
            staged_a = a;
            asm volatile("s_waitcnt vmcnt(0)" ::: "memory");
            __syncthreads();
        }

        int rowA = a * AT;
        int jb   = c * BT + wid * 32;           // this wave's 32 B rows
        const unsigned short* gB = Tb + (size_t)jb * D;

        // pre-scaled epilogue operands
        float gsj[2], gsi[4][4];
        #pragma unroll
        for (int n = 0; n < 2; ++n) gsj[n] = g2 * sq[jb + n * 16 + lr];
        #pragma unroll
        for (int m = 0; m < 4; ++m)
            #pragma unroll
            for (int r = 0; r < 4; ++r)
                gsi[m][r] = g2 * sq[rowA + m * 16 + lk * 4 + r];

        f32x4 acc[4][2];
        #pragma unroll
        for (int m = 0; m < 4; ++m)
            #pragma unroll
            for (int n = 0; n < 2; ++n)
                acc[m][n] = (f32x4){0.f, 0.f, 0.f, 0.f};

        // full-K sweep: A from LDS (shared by all 4 waves), B from L2.
        #pragma unroll
        for (int ks = 0; ks < 8; ++ks) {
            short8 av[4], bv[2];
            int ca = ks * 4 + lk;
            #pragma unroll
            for (int m = 0; m < 4; ++m) {
                int rA = m * 16 + lr;
                av[m] = *(const short8*)&As[rA * D + ((ca ^ (rA & 7)) << 3)];
            }
            #pragma unroll
            for (int n = 0; n < 2; ++n)
                bv[n] = *(const short8*)(gB + (size_t)(n * 16 + lr) * D + ca * 8);
            #pragma unroll
            for (int m = 0; m < 4; ++m)
                #pragma unroll
                for (int n = 0; n < 2; ++n)
                    acc[m][n] = __builtin_amdgcn_mfma_f32_16x16x32_bf16(
                                    av[m], bv[n], acc[m][n], 0, 0, 0);
        }

        // epilogue: e = min(2*g2*acc - gsi - gsj, 0); u = 2^e; sum 5 powers
        bool straddle = (c == (a >> 1));
        float local = 0.f;
        #pragma unroll
        for (int m = 0; m < 4; ++m) {
            #pragma unroll
            for (int r = 0; r < 4; ++r) {
                float gi_s = gsi[m][r];
                #pragma unroll
                for (int n = 0; n < 2; ++n) {
                    float tt = gi_s + gsj[n];
                    float e  = fminf(fmaf(g22, acc[m][n][r], -tt), 0.f);
                    float u  = EXP2F(e);
                    float u2 = u * u, u4 = u2 * u2, u8 = u4 * u4, u16 = u8 * u8;
                    float s5 = u + u2 + u4 + u8 + u16;
                    if (straddle) {
                        int gi = rowA + m * 16 + lk * 4 + r;
                        int gj = jb + n * 16 + lr;
                        float w = (gj > gi) ? 2.f : ((gj == gi) ? 1.f : 0.f);
                        local += w * s5;
                    } else {
                        local += s5;
                    }
                }
            }
        }
        if (!straddle) local *= 2.f;

        #pragma unroll
        for (int off = 32; off; off >>= 1) local += __shfl_xor(local, off, 64);
        if (lane == 0) {
            // sign: A band in src iff a<64; B band in src iff c<32
            float sign = ((a < NA / 2) == (c < NC / 2)) ? 1.f : -1.f;
            atomicAdd(&bins[((sw << 2) + wid) & (NBINS - 1)],
                      (double)(sign * local));
        }

        // advance
        ++c;
        if (c >= NC) { ++a; c = a >> 1; }
    }

    __syncthreads();
    if (t == 0) {
        __threadfence();
        unsigned old = atomicAdd(counter, 1u);
        if (old == NGRID - 1) {                 // last block finalizes
            __threadfence();
            double tot = 0.0;
            for (int i = 0; i < NBINS; ++i)
                tot += ((volatile double*)bins)[i];
            out[0] = (float)(tot / ((double)BHALF * (double)BHALF));
        }
    }
}

extern "C" void kernel_launch(void* const* d_in, const int* in_sizes, int n_in,
                              void* d_out, int out_size, void* d_ws, size_t ws_size,
                              hipStream_t stream) {
    const float* src = (const float*)d_in[0];
    const float* tar = (const float*)d_in[1];
    float* out = (float*)d_out;

    char* ws = (char*)d_ws;
    double*   sumsq   = (double*)(ws + 0);
    unsigned* counter = (unsigned*)(ws + 8);
    double*   bins    = (double*)(ws + 16);
    float*    colsum  = (float*)(ws + 1024);
    float*    sq      = (float*)(ws + 4096);
    unsigned short* Tb = (unsigned short*)(ws + 36864);

    hipMemsetAsync(ws, 0, 2048, stream);
    pre_kernel<<<256, 256, 0, stream>>>(src, tar, sq, colsum, sumsq, Tb);
    mmd_main<<<NGRID, 256, 0, stream>>>(Tb, sq, colsum, sumsq, bins, counter, out);
}

// Round 8
// 150.337 us; speedup vs baseline: 1.0771x; 1.0771x over previous
//
#include <hip/hip_runtime.h>

#define D      256
#define NROWS  8192
#define BHALF  4096
#define AT     64                      // A band rows per wave (in registers)
#define BTW    32                      // B band rows per unit
#define NBI    (NROWS / AT)            // 128 i-bands
#define NJB    (NROWS / BTW)           // 256 j-bands
#define NUNIT  16512                   // sum_bi (256 - 2*bi)
#define NGRID  512                     // 2 blocks/CU, 4 waves each
#define NWAVES (NGRID * 4)             // 2048
#define NBINS  64

typedef __attribute__((ext_vector_type(8))) short  short8;
typedef __attribute__((ext_vector_type(4))) float  f32x4;

// ws layout (memset zeroes [0..2048)):
//   0     double sumsq
//   8     unsigned counter
//   16    double bins[64]          -> ends 528
//   1024  float colsum[256]        -> ends 2048
//   4096  float sq[8192]           -> ends 36864
//   36864 bf16 Tb[8192][256] (4 MB) -> ends 4231168 (proven < ws_size)

__device__ __forceinline__ unsigned short f2bf(float f) {
    unsigned u = __builtin_bit_cast(unsigned, f);
    unsigned r = (u + 0x7fffu + ((u >> 16) & 1u)) >> 16;   // RNE (no NaN in data)
    return (unsigned short)r;
}

// ---------------------------------------------------------------- pass 1
__global__ __launch_bounds__(256)
void pre_kernel(const float* __restrict__ src, const float* __restrict__ tar,
                float* __restrict__ sq, float* __restrict__ colsum,
                double* __restrict__ sumsq, unsigned short* __restrict__ Tb) {
    __shared__ float cs[D];
    int t = threadIdx.x;
    cs[t] = 0.f;
    __syncthreads();

    int lane = t & 63, w = t >> 6;
    int rowBase = blockIdx.x * 32 + w * 8;

    float4 v[8];
    #pragma unroll
    for (int it = 0; it < 8; ++it) {
        int r = rowBase + it;
        const float* rowp = (r < BHALF) ? (src + (size_t)r * D)
                                        : (tar + (size_t)(r - BHALF) * D);
        v[it] = *(const float4*)(rowp + lane * 4);
    }

    float4 csum = make_float4(0.f, 0.f, 0.f, 0.f);
    float sqacc = 0.f;
    #pragma unroll
    for (int it = 0; it < 8; ++it) {
        int r = rowBase + it;
        ushort4 h;
        h.x = f2bf(v[it].x); h.y = f2bf(v[it].y);
        h.z = f2bf(v[it].z); h.w = f2bf(v[it].w);
        *(ushort4*)(Tb + (size_t)r * D + lane * 4) = h;
        csum.x += v[it].x; csum.y += v[it].y; csum.z += v[it].z; csum.w += v[it].w;
        float s = v[it].x * v[it].x + v[it].y * v[it].y +
                  v[it].z * v[it].z + v[it].w * v[it].w;
        #pragma unroll
        for (int off = 32; off; off >>= 1) s += __shfl_xor(s, off, 64);
        if (lane == 0) { sq[r] = s; sqacc += s; }
    }
    atomicAdd(&cs[lane * 4 + 0], csum.x);
    atomicAdd(&cs[lane * 4 + 1], csum.y);
    atomicAdd(&cs[lane * 4 + 2], csum.z);
    atomicAdd(&cs[lane * 4 + 3], csum.w);
    if (lane == 0) atomicAdd(sumsq, (double)sqacc);
    __syncthreads();
    atomicAdd(&colsum[t], cs[t]);
}

// ---------------------------------------------------------------- main
// Per wave: A band (64 rows, full K) in 128 VGPRs; stream B bands from L2.
// No LDS, no barriers — waves fully independent.
__global__ __launch_bounds__(256, 2)
void mmd_main(const unsigned short* __restrict__ Tb,
              const float* __restrict__ sq, const float* __restrict__ colsum,
              const double* __restrict__ sumsq,
              double* __restrict__ bins, unsigned* __restrict__ counter,
              float* __restrict__ out)
{
    int t = threadIdx.x, lane = t & 63, wid = t >> 6;
    int lr = lane & 15, lk = lane >> 4;

    // XCD-contiguous runs: blocks on one XCD get adjacent unit ranges
    int bid = blockIdx.x;
    int sw = (bid & 7) * (NGRID / 8) + (bid >> 3);
    int gw = sw * 4 + wid;                       // global wave id, 0..2047
    int ustart = (int)(((long)gw * NUNIT) / NWAVES);
    int uend   = (int)(((long)(gw + 1) * NUNIT) / NWAVES);

    // unit -> (bi, jb): bi in 0..127, jb in 2*bi .. 255
    int bi, jb;
    {
        int rem = ustart; bi = 0;
        while (rem >= NJB - 2 * bi) { rem -= NJB - 2 * bi; ++bi; }
        jb = 2 * bi + rem;
    }

    // bandwidth -> g2 (redundant per wave; overlaps first A load)
    float4 c4 = *(const float4*)(colsum + lane * 4);
    float s = c4.x * c4.x + c4.y * c4.y + c4.z * c4.z + c4.w * c4.w;
    #pragma unroll
    for (int off = 32; off; off >>= 1) s += __shfl_xor(s, off, 64);
    double sumL2 = 2.0 * (double)NROWS * (*sumsq) - 2.0 * (double)s;
    double bwd = sumL2 / ((double)NROWS * (double)NROWS - (double)NROWS) / 4.0;
    float g2  = (float)(1.4426950408889634 / (16.0 * bwd));
    float g22 = 2.f * g2;

    // A band fragments: aA[ks][m] = rows bi*64 + m*16 + lr, k = ks*32 + lk*8
    short8 aA[8][4];
    float  gsi[4][4];
    auto loadA = [&](int b) {
        const unsigned short* g = Tb + (size_t)b * AT * D;
        #pragma unroll
        for (int ks = 0; ks < 8; ++ks)
            #pragma unroll
            for (int m = 0; m < 4; ++m)
                aA[ks][m] = *(const short8*)(g + (m * 16 + lr) * D + ks * 32 + lk * 8);
        #pragma unroll
        for (int m = 0; m < 4; ++m)
            #pragma unroll
            for (int r = 0; r < 4; ++r)
                gsi[m][r] = g2 * sq[b * AT + m * 16 + lk * 4 + r];
    };
    loadA(bi);

    for (int u = ustart; u < uend; ++u) {
        const unsigned short* gB = Tb + (size_t)jb * BTW * D;
        float gsj[2];
        #pragma unroll
        for (int n = 0; n < 2; ++n) gsj[n] = g2 * sq[jb * BTW + n * 16 + lr];

        f32x4 acc[4][2];
        #pragma unroll
        for (int m = 0; m < 4; ++m)
            #pragma unroll
            for (int n = 0; n < 2; ++n)
                acc[m][n] = (f32x4){0.f, 0.f, 0.f, 0.f};

        // 16 independent B loads + 64 MFMAs; compiler pipelines across ks
        #pragma unroll
        for (int ks = 0; ks < 8; ++ks) {
            short8 bv[2];
            #pragma unroll
            for (int n = 0; n < 2; ++n)
                bv[n] = *(const short8*)(gB + (size_t)(n * 16 + lr) * D + ks * 32 + lk * 8);
            #pragma unroll
            for (int m = 0; m < 4; ++m)
                #pragma unroll
                for (int n = 0; n < 2; ++n)
                    acc[m][n] = __builtin_amdgcn_mfma_f32_16x16x32_bf16(
                                    aA[ks][m], bv[n], acc[m][n], 0, 0, 0);
        }

        // epilogue: e = min(2*g2*acc - gsi - gsj, 0); u = 2^e; 5 powers
        bool straddle = ((jb >> 1) == bi);
        float local = 0.f;
        #pragma unroll
        for (int m = 0; m < 4; ++m) {
            #pragma unroll
            for (int r = 0; r < 4; ++r) {
                float gi_s = gsi[m][r];
                #pragma unroll
                for (int n = 0; n < 2; ++n) {
                    float tt = gi_s + gsj[n];
                    float e  = fminf(fmaf(g22, acc[m][n][r], -tt), 0.f);
                    float uu = exp2f(e);
                    float u2 = uu * uu, u4 = u2 * u2, u8 = u4 * u4, u16 = u8 * u8;
                    float s5 = uu + u2 + u4 + u8 + u16;
                    if (straddle) {
                        int gi = bi * AT + m * 16 + lk * 4 + r;
                        int gj = jb * BTW + n * 16 + lr;
                        float w = (gj > gi) ? 2.f : ((gj == gi) ? 1.f : 0.f);
                        local += w * s5;
                    } else {
                        local += s5;
                    }
                }
            }
        }
        if (!straddle) local *= 2.f;

        #pragma unroll
        for (int off = 32; off; off >>= 1) local += __shfl_xor(local, off, 64);
        if (lane == 0) {
            float sign = ((bi < NBI / 2) == (jb < NJB / 2)) ? 1.f : -1.f;
            atomicAdd(&bins[gw & (NBINS - 1)], (double)(sign * local));
        }

        // advance; reload A only on band change (wave-uniform)
        ++jb;
        if (jb >= NJB) {
            ++bi; jb = 2 * bi;
            if (u + 1 < uend) loadA(bi);
        }
    }

    __syncthreads();
    if (t == 0) {
        __threadfence();
        unsigned old = atomicAdd(counter, 1u);
        if (old == NGRID - 1) {                 // last block finalizes
            __threadfence();
            double tot = 0.0;
            for (int i = 0; i < NBINS; ++i)
                tot += ((volatile double*)bins)[i];
            out[0] = (float)(tot / ((double)BHALF * (double)BHALF));
        }
    }
}

extern "C" void kernel_launch(void* const* d_in, const int* in_sizes, int n_in,
                              void* d_out, int out_size, void* d_ws, size_t ws_size,
                              hipStream_t stream) {
    const float* src = (const float*)d_in[0];
    const float* tar = (const float*)d_in[1];
    float* out = (float*)d_out;

    char* ws = (char*)d_ws;
    double*   sumsq   = (double*)(ws + 0);
    unsigned* counter = (unsigned*)(ws + 8);
    double*   bins    = (double*)(ws + 16);
    float*    colsum  = (float*)(ws + 1024);
    float*    sq      = (float*)(ws + 4096);
    unsigned short* Tb = (unsigned short*)(ws + 36864);

    hipMemsetAsync(ws, 0, 2048, stream);
    pre_kernel<<<256, 256, 0, stream>>>(src, tar, sq, colsum, sumsq, Tb);
    mmd_main<<<NGRID, 256, 0, stream>>>(Tb, sq, colsum, sumsq, bins, counter, out);
}